// Round 15
// baseline (405.350 us; speedup 1.0000x reference)
//
#include <hip/hip_runtime.h>

// MHA forward for B=4, S=2048, D=1024, H=16, dk=64.
// Outputs: d_out[0 .. 8388607]            = (ctx @ w_o)  fp32  [B,S,D]
//          d_out[8388608 .. 276824063]    = attn          fp32  [B,H,S,S]

typedef __attribute__((ext_vector_type(8))) short bf16x8;
typedef __attribute__((ext_vector_type(4))) float f32x4;
typedef __attribute__((ext_vector_type(8))) unsigned short u16x8;
typedef __attribute__((ext_vector_type(4))) unsigned int u32x4;

__device__ __forceinline__ unsigned short f2bf(float x) {
    unsigned u = __float_as_uint(x);
    u += 0x7FFFu + ((u >> 16) & 1u);          // RNE
    return (unsigned short)(u >> 16);
}

// pack 4 fp32 -> 4 bf16 (8B) via 2x v_cvt_pk_bf16_f32 (RNE)
__device__ __forceinline__ uint2 pk4(f32x4 v) {
    unsigned r0, r1;
    asm("v_cvt_pk_bf16_f32 %0, %1, %2" : "=v"(r0) : "v"(v[0]), "v"(v[1]));
    asm("v_cvt_pk_bf16_f32 %0, %1, %2" : "=v"(r1) : "v"(v[2]), "v"(v[3]));
    return make_uint2(r0, r1);
}

__device__ __forceinline__ void gll16(const void* g, void* l) {
    __builtin_amdgcn_global_load_lds(
        (const __attribute__((address_space(1))) void*)g,
        (__attribute__((address_space(3))) void*)l, 16, 0, 0);
}

// ---------------- fp32 -> bf16 convert for q,k,v ----------------
__global__ __launch_bounds__(256) void cvt3(
    const float* __restrict__ q, const float* __restrict__ k, const float* __restrict__ v,
    unsigned short* __restrict__ qb, unsigned short* __restrict__ kb, unsigned short* __restrict__ vb)
{
    int b = blockIdx.x;             // 12288 blocks: 4096 per input
    int which = b >> 12;
    const float* src = which == 0 ? q : (which == 1 ? k : v);
    unsigned short* dst = which == 0 ? qb : (which == 1 ? kb : vb);
    size_t off = ((size_t)(b & 4095) * 256 + threadIdx.x) * 8;
    float4 x0 = *(const float4*)(src + off);
    float4 x1 = *(const float4*)(src + off + 4);
    u16x8 o;
    o[0] = f2bf(x0.x); o[1] = f2bf(x0.y); o[2] = f2bf(x0.z); o[3] = f2bf(x0.w);
    o[4] = f2bf(x1.x); o[5] = f2bf(x1.y); o[6] = f2bf(x1.z); o[7] = f2bf(x1.w);
    *(u16x8*)(dst + off) = o;
}

// ------- weight transpose: W[k][n] fp32 -> Wt[n][k] bf16 -------
// w_q pre-scaled by (1/8)*log2(e) so attn scores are base-2 exponents directly.
__global__ __launch_bounds__(256) void wtrans(
    const float* __restrict__ w0, const float* __restrict__ w1,
    const float* __restrict__ w2, const float* __restrict__ w3,
    unsigned short* __restrict__ o0, unsigned short* __restrict__ o1,
    unsigned short* __restrict__ o2, unsigned short* __restrict__ o3)
{
    __shared__ float T[64 * 68];
    int b = blockIdx.x;                 // 1024: 4 weights x 256 tiles
    int wi = b >> 8, tile = b & 255;
    int k0 = (tile >> 4) * 64, n0 = (tile & 15) * 64;
    const float* W = wi == 0 ? w0 : (wi == 1 ? w1 : (wi == 2 ? w2 : w3));
    unsigned short* O = wi == 0 ? o0 : (wi == 1 ? o1 : (wi == 2 ? o2 : o3));
    float scale = (wi == 0) ? 0.18033688011112042f : 1.0f;  // 0.125 * log2(e)
    int t = threadIdx.x;
#pragma unroll
    for (int i = 0; i < 4; i++) {
        int idx = i * 256 + t;          // 0..1023
        int r = idx >> 4, ch = idx & 15;
        float4 vv = *(const float4*)(W + (size_t)(k0 + r) * 1024 + n0 + ch * 4);
        *(float4*)(&T[r * 68 + ch * 4]) = vv;
    }
    __syncthreads();
#pragma unroll
    for (int i = 0; i < 2; i++) {
        int idx = i * 256 + t;          // 0..511
        int n = idx >> 3, ch = idx & 7;
        u16x8 o;
#pragma unroll
        for (int jj = 0; jj < 8; jj++) o[jj] = f2bf(T[(ch * 8 + jj) * 68 + n] * scale);
        *(u16x8*)(O + (size_t)(n0 + n) * 1024 + k0 + ch * 8) = o;
    }
}

// ---------------- 128x128 bf16 MFMA GEMM, K=1024, BK=32, m97 structure ----------------
template<int MODE>
__global__ __launch_bounds__(256) void gemm128(
    const unsigned short* __restrict__ A0, const unsigned short* __restrict__ A1, const unsigned short* __restrict__ A2,
    const unsigned short* __restrict__ B0, const unsigned short* __restrict__ B1, const unsigned short* __restrict__ B2,
    void* O0, void* O1, void* O2)
{
    constexpr int K = 1024, NK = 32;
    __shared__ unsigned short As[2][128 * 32];
    __shared__ unsigned short Bs[2][128 * 32];
    const int t = threadIdx.x, lane = t & 63, w = t >> 6;
    const int z = blockIdx.z;
    const unsigned short* A  = z == 0 ? A0 : (z == 1 ? A1 : A2);
    const unsigned short* Bt = z == 0 ? B0 : (z == 1 ? B1 : B2);
    void* O = z == 0 ? O0 : (z == 1 ? O1 : O2);
    const bool vt = (MODE == 0) && (z == 2);
    int bid = blockIdx.x;               // 0..511
    int xcd = bid & 7, seq = bid >> 3;
    int npan = seq >> 3, mpan = ((seq & 7) << 3) + xcd;
    int m0 = mpan * 128, n0 = npan * 128;
    int wr = w >> 1, wc = w & 1;
    int qhi = lane >> 4, rr = lane & 15;

    auto stage = [&](int buf, int kt) {
#pragma unroll
        for (int i = 0; i < 2; i++) {
            int o = ((w * 2 + i) << 10) + (lane << 4);
            int r = o >> 6, c = o & 63;
            int sc = c ^ (((r >> 1) & 3) << 4);      // inverse-swizzled source
            gll16((const char*)A + ((size_t)(m0 + r) * K + kt * 32) * 2 + sc,
                  (char*)&As[buf][0] + ((w * 2 + i) << 10));
        }
#pragma unroll
        for (int i = 0; i < 2; i++) {
            int o = ((w * 2 + i) << 10) + (lane << 4);
            int r = o >> 6, c = o & 63;
            int sc = c ^ (((r >> 1) & 3) << 4);
            gll16((const char*)Bt + ((size_t)(n0 + r) * K + kt * 32) * 2 + sc,
                  (char*)&Bs[buf][0] + ((w * 2 + i) << 10));
        }
    };

    f32x4 acc[4][4] = {};
    stage(0, 0);
    __syncthreads();
    int buf = 0;
    for (int kt = 0; kt < NK; kt++) {
        if (kt + 1 < NK) stage(buf ^ 1, kt + 1);
        const char* as = (const char*)&As[buf][0];
        const char* bs = (const char*)&Bs[buf][0];
        bf16x8 a[4], b[4];
#pragma unroll
        for (int mi = 0; mi < 4; mi++) {
            int r = wr * 64 + mi * 16 + rr;
            a[mi] = *(const bf16x8*)(as + r * 64 + ((qhi << 4) ^ (((r >> 1) & 3) << 4)));
        }
#pragma unroll
        for (int ni = 0; ni < 4; ni++) {
            int r = wc * 64 + ni * 16 + rr;
            b[ni] = *(const bf16x8*)(bs + r * 64 + ((qhi << 4) ^ (((r >> 1) & 3) << 4)));
        }
        if (vt) {
#pragma unroll
            for (int mi = 0; mi < 4; mi++)
#pragma unroll
                for (int ni = 0; ni < 4; ni++)
                    acc[mi][ni] = __builtin_amdgcn_mfma_f32_16x16x32_bf16(a[mi], b[ni], acc[mi][ni], 0, 0, 0);
        } else {
#pragma unroll
            for (int mi = 0; mi < 4; mi++)
#pragma unroll
                for (int ni = 0; ni < 4; ni++)
                    acc[mi][ni] = __builtin_amdgcn_mfma_f32_16x16x32_bf16(b[ni], a[mi], acc[mi][ni], 0, 0, 0);
        }
        __syncthreads();
        buf ^= 1;
    }

    if (MODE == 1) {
#pragma unroll
        for (int mi = 0; mi < 4; mi++) {
            int m = m0 + wr * 64 + mi * 16 + rr;
#pragma unroll
            for (int ni = 0; ni < 4; ni++) {
                int n = n0 + wc * 64 + ni * 16 + qhi * 4;
                f32x4 o = acc[mi][ni];
                __builtin_nontemporal_store(o, (f32x4*)((float*)O + (size_t)m * 1024 + n));
            }
        }
    } else if (vt) {
        unsigned short* Vt = (unsigned short*)O;
#pragma unroll
        for (int mi = 0; mi < 4; mi++) {
            int m = m0 + wr * 64 + mi * 16 + qhi * 4;
#pragma unroll
            for (int ni = 0; ni < 4; ni++) {
                int n = n0 + wc * 64 + ni * 16 + rr;
                int bh = (m >> 11) * 16 + (n >> 6);
                *(uint2*)(Vt + ((size_t)bh * 64 + (n & 63)) * 2048 + (m & 2047)) = pk4(acc[mi][ni]);
            }
        }
    } else {
        unsigned short* Oh = (unsigned short*)O;
#pragma unroll
        for (int mi = 0; mi < 4; mi++) {
            int m = m0 + wr * 64 + mi * 16 + rr;
#pragma unroll
            for (int ni = 0; ni < 4; ni++) {
                int n = n0 + wc * 64 + ni * 16 + qhi * 4;
                size_t idx = (((size_t)((m >> 11) * 16 + (n >> 6))) * 2048 + (m & 2047)) * 64 + (n & 63);
                *(uint2*)(Oh + idx) = pk4(acc[mi][ni]);
            }
        }
    }
}

// ------- attention: 2-chain pipeline, 128 q-rows/block (2 tiles of 64), 4 waves -------
// Phase A: pass1(tile0). Phase B: pass2(tile0) MERGED with pass1(tile1) — shared K
// frags/staging. Phase C: pass2(tile1). Scores are base-2 (log2e folded into wq).
// attn stores: per-wave LDS transpose -> 4x (4 rows x 256B) nontemporal stores.
__global__ __launch_bounds__(256, 3) void attn2(
    const unsigned short* __restrict__ Qh, const unsigned short* __restrict__ Kh,
    const unsigned short* __restrict__ Vt, float* __restrict__ attn,
    unsigned short* __restrict__ ctx)
{
    __shared__ unsigned short Ks[2][64 * 64];   // [kc][d], swizzled 128B rows
    __shared__ unsigned short Vs[2][64 * 64];   // [d][kc], swizzled
    __shared__ float St[4][1024];               // per-wave 16x64 fp32 staging, slot^rr swizzle
    const int t = threadIdx.x, lane = t & 63, w = t >> 6;
    int bid = blockIdx.x;
    int rm = (bid & 7) * 128 + (bid >> 3);      // XCD swizzle
    int bh = rm >> 4, rb = rm & 15;
    int qhi = lane >> 4, rr = lane & 15;
    int q00 = rb * 128 + w * 16;                // tile0 rows for this wave
    int q01 = q00 + 64;                         // tile1 rows

    const unsigned short* qb0 = Qh + ((size_t)bh * 2048 + q00 + rr) * 64;
    const unsigned short* qb1 = Qh + ((size_t)bh * 2048 + q01 + rr) * 64;
    bf16x8 aqA0 = *(const bf16x8*)(qb0 + qhi * 8);
    bf16x8 aqA1 = *(const bf16x8*)(qb0 + 32 + qhi * 8);
    bf16x8 aqB0 = *(const bf16x8*)(qb1 + qhi * 8);
    bf16x8 aqB1 = *(const bf16x8*)(qb1 + 32 + qhi * 8);

    auto stageK = [&](int buf, int ct) {
#pragma unroll
        for (int i = 0; i < 2; i++) {
            int o = ((w * 2 + i) << 10) + (lane << 4);
            int r = o >> 7, c = o & 127;
            int sc = c ^ ((r & 7) << 4);
            gll16((const char*)Kh + (size_t)(bh * 2048 + ct * 64 + r) * 128 + sc,
                  (char*)&Ks[buf][0] + ((w * 2 + i) << 10));
        }
    };
    auto stageV = [&](int buf, int ct) {
#pragma unroll
        for (int i = 0; i < 2; i++) {
            int o = ((w * 2 + i) << 10) + (lane << 4);
            int r = o >> 7, c = o & 127;
            int sc = c ^ ((r & 7) << 4);
            gll16((const char*)Vt + (size_t)(bh * 64 + r) * 4096 + ct * 128 + sc,
                  (char*)&Vs[buf][0] + ((w * 2 + i) << 10));
        }
    };

    float* ab = attn + (size_t)bh * 2048 * 2048;
    float* stw = &St[w][0];

    // ---- phase A: pass1(tile0) ----
    f32x4 sv = {0.f, 0.f, 0.f, 0.f};
    stageK(0, 0);
    __syncthreads();
    int buf = 0;
    for (int ct = 0; ct < 32; ct++) {
        if (ct < 31) stageK(buf ^ 1, ct + 1);
        const char* ks = (const char*)&Ks[buf][0];
#pragma unroll
        for (int n = 0; n < 4; n++) {
            int r = n * 16 + rr;
            int sw = (r & 7) << 4;
            bf16x8 b0 = *(const bf16x8*)(ks + r * 128 + ((qhi << 4) ^ sw));
            bf16x8 b1 = *(const bf16x8*)(ks + r * 128 + ((64 | (qhi << 4)) ^ sw));
            f32x4 z4 = {0.f, 0.f, 0.f, 0.f};
            f32x4 s = __builtin_amdgcn_mfma_f32_16x16x32_bf16(b0, aqA0, z4, 0, 0, 0);
            s = __builtin_amdgcn_mfma_f32_16x16x32_bf16(b1, aqA1, s, 0, 0, 0);
#pragma unroll
            for (int j = 0; j < 4; j++) sv[j] += exp2f(s[j]);
        }
        __syncthreads();
        buf ^= 1;
    }
    float lsum = sv[0] + sv[1] + sv[2] + sv[3];
    lsum += __shfl_xor(lsum, 16);
    lsum += __shfl_xor(lsum, 32);
    float lr2a = -__log2f(lsum);

    // ---- phase B: pass2(tile0) merged with pass1(tile1); shared K frags ----
    f32x4 sv1 = {0.f, 0.f, 0.f, 0.f};
    f32x4 acco[4] = {};
    stageK(0, 0); stageV(0, 0);
    __syncthreads();
    buf = 0;
    for (int ct = 0; ct < 32; ct++) {
        if (ct < 31) { stageK(buf ^ 1, ct + 1); stageV(buf ^ 1, ct + 1); }
        const char* ks = (const char*)&Ks[buf][0];
        f32x4 s0[4];
#pragma unroll
        for (int n = 0; n < 4; n++) {
            int r = n * 16 + rr;
            int sw = (r & 7) << 4;
            bf16x8 b0 = *(const bf16x8*)(ks + r * 128 + ((qhi << 4) ^ sw));
            bf16x8 b1 = *(const bf16x8*)(ks + r * 128 + ((64 | (qhi << 4)) ^ sw));
            f32x4 z4 = {0.f, 0.f, 0.f, 0.f};
            s0[n] = __builtin_amdgcn_mfma_f32_16x16x32_bf16(b0, aqA0, z4, 0, 0, 0);
            s0[n] = __builtin_amdgcn_mfma_f32_16x16x32_bf16(b1, aqA1, s0[n], 0, 0, 0);
            f32x4 s1 = __builtin_amdgcn_mfma_f32_16x16x32_bf16(b0, aqB0, z4, 0, 0, 0);
            s1 = __builtin_amdgcn_mfma_f32_16x16x32_bf16(b1, aqB1, s1, 0, 0, 0);
#pragma unroll
            for (int j = 0; j < 4; j++) sv1[j] += exp2f(s1[j]);
        }
        unsigned wA[4], wB[4];
#pragma unroll
        for (int n = 0; n < 4; n++) {
            f32x4 pv;
#pragma unroll
            for (int j = 0; j < 4; j++) pv[j] = exp2f(s0[n][j] + lr2a);
            *(f32x4*)(stw + rr * 64 + (((n * 4 + qhi) ^ rr) << 2)) = pv;
            asm("v_cvt_pk_bf16_f32 %0, %1, %2" : "=v"(wA[n]) : "v"(pv[0]), "v"(pv[1]));
            asm("v_cvt_pk_bf16_f32 %0, %1, %2" : "=v"(wB[n]) : "v"(pv[2]), "v"(pv[3]));
        }
        const char* vs = (const char*)&Vs[buf][0];
#pragma unroll
        for (int kb = 0; kb < 2; kb++) {
            u32x4 fw = {wA[2 * kb], wB[2 * kb], wA[2 * kb + 1], wB[2 * kb + 1]};
            bf16x8 pf = *(bf16x8*)&fw;
#pragma unroll
            for (int db = 0; db < 4; db++) {
                int r = db * 16 + rr;
                int sw = (r & 7) << 4;
                uint2 lo8 = *(const uint2*)(vs + r * 128 + ((kb * 64 + qhi * 8) ^ sw));
                uint2 hi8 = *(const uint2*)(vs + r * 128 + ((kb * 64 + 32 + qhi * 8) ^ sw));
                u32x4 vw = {lo8.x, lo8.y, hi8.x, hi8.y};
                bf16x8 vf = *(bf16x8*)&vw;
                acco[db] = __builtin_amdgcn_mfma_f32_16x16x32_bf16(vf, pf, acco[db], 0, 0, 0);
            }
        }
#pragma unroll
        for (int i = 0; i < 4; i++) {
            int r = 4 * i + qhi;
            f32x4 vvv = *(const f32x4*)(stw + r * 64 + ((rr ^ r) << 2));
            __builtin_nontemporal_store(vvv,
                (f32x4*)(ab + (size_t)(q00 + r) * 2048 + ct * 64 + rr * 4));
        }
        asm volatile("s_waitcnt vmcnt(4)" ::: "memory");
        __builtin_amdgcn_s_barrier();
        buf ^= 1;
    }
    int b_ = bh >> 4, h_ = bh & 15;
    {
        unsigned short* cw = ctx + ((size_t)b_ * 2048 + q00 + rr) * 1024 + h_ * 64;
#pragma unroll
        for (int db = 0; db < 4; db++)
            *(uint2*)(cw + db * 16 + qhi * 4) = pk4(acco[db]);
    }
    float lsum1 = sv1[0] + sv1[1] + sv1[2] + sv1[3];
    lsum1 += __shfl_xor(lsum1, 16);
    lsum1 += __shfl_xor(lsum1, 32);
    float lr2b = -__log2f(lsum1);

    // ---- phase C: pass2(tile1) ----
#pragma unroll
    for (int db = 0; db < 4; db++) acco[db] = (f32x4){0.f, 0.f, 0.f, 0.f};
    stageK(0, 0); stageV(0, 0);
    __syncthreads();
    buf = 0;
    for (int ct = 0; ct < 32; ct++) {
        if (ct < 31) { stageK(buf ^ 1, ct + 1); stageV(buf ^ 1, ct + 1); }
        const char* ks = (const char*)&Ks[buf][0];
        f32x4 s[4];
#pragma unroll
        for (int n = 0; n < 4; n++) {
            int r = n * 16 + rr;
            int sw = (r & 7) << 4;
            bf16x8 b0 = *(const bf16x8*)(ks + r * 128 + ((qhi << 4) ^ sw));
            bf16x8 b1 = *(const bf16x8*)(ks + r * 128 + ((64 | (qhi << 4)) ^ sw));
            f32x4 z4 = {0.f, 0.f, 0.f, 0.f};
            s[n] = __builtin_amdgcn_mfma_f32_16x16x32_bf16(b0, aqB0, z4, 0, 0, 0);
            s[n] = __builtin_amdgcn_mfma_f32_16x16x32_bf16(b1, aqB1, s[n], 0, 0, 0);
        }
        unsigned wA[4], wB[4];
#pragma unroll
        for (int n = 0; n < 4; n++) {
            f32x4 pv;
#pragma unroll
            for (int j = 0; j < 4; j++) pv[j] = exp2f(s[n][j] + lr2b);
            *(f32x4*)(stw + rr * 64 + (((n * 4 + qhi) ^ rr) << 2)) = pv;
            asm("v_cvt_pk_bf16_f32 %0, %1, %2" : "=v"(wA[n]) : "v"(pv[0]), "v"(pv[1]));
            asm("v_cvt_pk_bf16_f32 %0, %1, %2" : "=v"(wB[n]) : "v"(pv[2]), "v"(pv[3]));
        }
        const char* vs = (const char*)&Vs[buf][0];
#pragma unroll
        for (int kb = 0; kb < 2; kb++) {
            u32x4 fw = {wA[2 * kb], wB[2 * kb], wA[2 * kb + 1], wB[2 * kb + 1]};
            bf16x8 pf = *(bf16x8*)&fw;
#pragma unroll
            for (int db = 0; db < 4; db++) {
                int r = db * 16 + rr;
                int sw = (r & 7) << 4;
                uint2 lo8 = *(const uint2*)(vs + r * 128 + ((kb * 64 + qhi * 8) ^ sw));
                uint2 hi8 = *(const uint2*)(vs + r * 128 + ((kb * 64 + 32 + qhi * 8) ^ sw));
                u32x4 vw = {lo8.x, lo8.y, hi8.x, hi8.y};
                bf16x8 vf = *(bf16x8*)&vw;
                acco[db] = __builtin_amdgcn_mfma_f32_16x16x32_bf16(vf, pf, acco[db], 0, 0, 0);
            }
        }
#pragma unroll
        for (int i = 0; i < 4; i++) {
            int r = 4 * i + qhi;
            f32x4 vvv = *(const f32x4*)(stw + r * 64 + ((rr ^ r) << 2));
            __builtin_nontemporal_store(vvv,
                (f32x4*)(ab + (size_t)(q01 + r) * 2048 + ct * 64 + rr * 4));
        }
        asm volatile("s_waitcnt vmcnt(4)" ::: "memory");
        __builtin_amdgcn_s_barrier();
        buf ^= 1;
    }
    {
        unsigned short* cw = ctx + ((size_t)b_ * 2048 + q01 + rr) * 1024 + h_ * 64;
#pragma unroll
        for (int db = 0; db < 4; db++)
            *(uint2*)(cw + db * 16 + qhi * 4) = pk4(acco[db]);
    }
}

extern "C" void kernel_launch(void* const* d_in, const int* in_sizes, int n_in,
                              void* d_out, int out_size, void* d_ws, size_t ws_size,
                              hipStream_t stream)
{
    (void)in_sizes; (void)n_in; (void)out_size; (void)ws_size;
    const float* q  = (const float*)d_in[0];
    const float* k  = (const float*)d_in[1];
    const float* v  = (const float*)d_in[2];
    const float* wq = (const float*)d_in[3];
    const float* wk = (const float*)d_in[4];
    const float* wv = (const float*)d_in[5];
    const float* wo = (const float*)d_in[6];
    char* ws = (char*)d_ws;
    const size_t M1 = 1ull << 20;
    unsigned short* qbf = (unsigned short*)(ws);
    unsigned short* kbf = (unsigned short*)(ws + 16 * M1);
    unsigned short* vbf = (unsigned short*)(ws + 32 * M1);
    unsigned short* wqt = (unsigned short*)(ws + 48 * M1);
    unsigned short* wkt = (unsigned short*)(ws + 50 * M1);
    unsigned short* wvt = (unsigned short*)(ws + 52 * M1);
    unsigned short* wot = (unsigned short*)(ws + 54 * M1);
    unsigned short* Qh  = (unsigned short*)(ws + 56 * M1);
    unsigned short* Kh  = (unsigned short*)(ws + 72 * M1);
    unsigned short* Vt  = (unsigned short*)(ws + 88 * M1);
    unsigned short* ctx = kbf;    // dead after projections
    float* out0 = (float*)d_out;
    float* attn = out0 + (size_t)8192 * 1024;

    cvt3<<<12288, 256, 0, stream>>>(q, k, v, qbf, kbf, vbf);
    wtrans<<<1024, 256, 0, stream>>>(wq, wk, wv, wo, wqt, wkt, wvt, wot);
    gemm128<0><<<dim3(512, 1, 3), 256, 0, stream>>>(qbf, kbf, vbf, wqt, wkt, wvt,
                                                    (void*)Qh, (void*)Kh, (void*)Vt);
    attn2<<<1024, 256, 0, stream>>>(Qh, Kh, Vt, attn, ctx);
    gemm128<1><<<dim3(512, 1, 1), 256, 0, stream>>>(ctx, ctx, ctx, wot, wot, wot,
                                                    (void*)out0, (void*)out0, (void*)out0);
}

// Round 18
// 404.999 us; speedup vs baseline: 1.0009x; 1.0009x over previous
//
#include <hip/hip_runtime.h>

// MHA forward for B=4, S=2048, D=1024, H=16, dk=64.
// Outputs: d_out[0 .. 8388607]            = (ctx @ w_o)  fp32  [B,S,D]
//          d_out[8388608 .. 276824063]    = attn          fp32  [B,H,S,S]
//
// FINAL (banked round-11/15 artifact, 405 us):
//  - bf16 MFMA end-to-end; 1/sqrt(dk) and log2(e) folded into w_q at transpose time
//  - proj GEMM: m97 structure (global_load_lds w16, XOR-swizzled LDS, dbuf, XCD swizzle)
//  - attention: 2-chain flash (pass1(t0); pass2(t0)||pass1(t1) shared-K; pass2(t1)),
//    attn written via per-wave LDS transpose -> 4x(4 rows x 256B) nontemporal stores
//  - NOTE: 4-tile chain variants (256 rows/block, 512 blocks) NaN deterministically
//    (rounds 12-17, unidentified defect) — do not resurrect without new evidence.

typedef __attribute__((ext_vector_type(8))) short bf16x8;
typedef __attribute__((ext_vector_type(4))) float f32x4;
typedef __attribute__((ext_vector_type(8))) unsigned short u16x8;
typedef __attribute__((ext_vector_type(4))) unsigned int u32x4;

__device__ __forceinline__ unsigned short f2bf(float x) {
    unsigned u = __float_as_uint(x);
    u += 0x7FFFu + ((u >> 16) & 1u);          // RNE
    return (unsigned short)(u >> 16);
}

// pack 4 fp32 -> 4 bf16 (8B) via 2x v_cvt_pk_bf16_f32 (RNE)
__device__ __forceinline__ uint2 pk4(f32x4 v) {
    unsigned r0, r1;
    asm("v_cvt_pk_bf16_f32 %0, %1, %2" : "=v"(r0) : "v"(v[0]), "v"(v[1]));
    asm("v_cvt_pk_bf16_f32 %0, %1, %2" : "=v"(r1) : "v"(v[2]), "v"(v[3]));
    return make_uint2(r0, r1);
}

__device__ __forceinline__ void gll16(const void* g, void* l) {
    __builtin_amdgcn_global_load_lds(
        (const __attribute__((address_space(1))) void*)g,
        (__attribute__((address_space(3))) void*)l, 16, 0, 0);
}

// ---------------- fp32 -> bf16 convert for q,k,v ----------------
__global__ __launch_bounds__(256) void cvt3(
    const float* __restrict__ q, const float* __restrict__ k, const float* __restrict__ v,
    unsigned short* __restrict__ qb, unsigned short* __restrict__ kb, unsigned short* __restrict__ vb)
{
    int b = blockIdx.x;             // 12288 blocks: 4096 per input
    int which = b >> 12;
    const float* src = which == 0 ? q : (which == 1 ? k : v);
    unsigned short* dst = which == 0 ? qb : (which == 1 ? kb : vb);
    size_t off = ((size_t)(b & 4095) * 256 + threadIdx.x) * 8;
    float4 x0 = *(const float4*)(src + off);
    float4 x1 = *(const float4*)(src + off + 4);
    u16x8 o;
    o[0] = f2bf(x0.x); o[1] = f2bf(x0.y); o[2] = f2bf(x0.z); o[3] = f2bf(x0.w);
    o[4] = f2bf(x1.x); o[5] = f2bf(x1.y); o[6] = f2bf(x1.z); o[7] = f2bf(x1.w);
    *(u16x8*)(dst + off) = o;
}

// ------- weight transpose: W[k][n] fp32 -> Wt[n][k] bf16 -------
// w_q pre-scaled by (1/8)*log2(e) so attn scores are base-2 exponents directly.
__global__ __launch_bounds__(256) void wtrans(
    const float* __restrict__ w0, const float* __restrict__ w1,
    const float* __restrict__ w2, const float* __restrict__ w3,
    unsigned short* __restrict__ o0, unsigned short* __restrict__ o1,
    unsigned short* __restrict__ o2, unsigned short* __restrict__ o3)
{
    __shared__ float T[64 * 68];
    int b = blockIdx.x;                 // 1024: 4 weights x 256 tiles
    int wi = b >> 8, tile = b & 255;
    int k0 = (tile >> 4) * 64, n0 = (tile & 15) * 64;
    const float* W = wi == 0 ? w0 : (wi == 1 ? w1 : (wi == 2 ? w2 : w3));
    unsigned short* O = wi == 0 ? o0 : (wi == 1 ? o1 : (wi == 2 ? o2 : o3));
    float scale = (wi == 0) ? 0.18033688011112042f : 1.0f;  // 0.125 * log2(e)
    int t = threadIdx.x;
#pragma unroll
    for (int i = 0; i < 4; i++) {
        int idx = i * 256 + t;          // 0..1023
        int r = idx >> 4, ch = idx & 15;
        float4 vv = *(const float4*)(W + (size_t)(k0 + r) * 1024 + n0 + ch * 4);
        *(float4*)(&T[r * 68 + ch * 4]) = vv;
    }
    __syncthreads();
#pragma unroll
    for (int i = 0; i < 2; i++) {
        int idx = i * 256 + t;          // 0..511
        int n = idx >> 3, ch = idx & 7;
        u16x8 o;
#pragma unroll
        for (int jj = 0; jj < 8; jj++) o[jj] = f2bf(T[(ch * 8 + jj) * 68 + n] * scale);
        *(u16x8*)(O + (size_t)(n0 + n) * 1024 + k0 + ch * 8) = o;
    }
}

// ---------------- 128x128 bf16 MFMA GEMM, K=1024, BK=32, m97 structure ----------------
template<int MODE>
__global__ __launch_bounds__(256) void gemm128(
    const unsigned short* __restrict__ A0, const unsigned short* __restrict__ A1, const unsigned short* __restrict__ A2,
    const unsigned short* __restrict__ B0, const unsigned short* __restrict__ B1, const unsigned short* __restrict__ B2,
    void* O0, void* O1, void* O2)
{
    constexpr int K = 1024, NK = 32;
    __shared__ unsigned short As[2][128 * 32];
    __shared__ unsigned short Bs[2][128 * 32];
    const int t = threadIdx.x, lane = t & 63, w = t >> 6;
    const int z = blockIdx.z;
    const unsigned short* A  = z == 0 ? A0 : (z == 1 ? A1 : A2);
    const unsigned short* Bt = z == 0 ? B0 : (z == 1 ? B1 : B2);
    void* O = z == 0 ? O0 : (z == 1 ? O1 : O2);
    const bool vt = (MODE == 0) && (z == 2);
    int bid = blockIdx.x;               // 0..511
    int xcd = bid & 7, seq = bid >> 3;
    int npan = seq >> 3, mpan = ((seq & 7) << 3) + xcd;
    int m0 = mpan * 128, n0 = npan * 128;
    int wr = w >> 1, wc = w & 1;
    int qhi = lane >> 4, rr = lane & 15;

    auto stage = [&](int buf, int kt) {
#pragma unroll
        for (int i = 0; i < 2; i++) {
            int o = ((w * 2 + i) << 10) + (lane << 4);
            int r = o >> 6, c = o & 63;
            int sc = c ^ (((r >> 1) & 3) << 4);      // inverse-swizzled source
            gll16((const char*)A + ((size_t)(m0 + r) * K + kt * 32) * 2 + sc,
                  (char*)&As[buf][0] + ((w * 2 + i) << 10));
        }
#pragma unroll
        for (int i = 0; i < 2; i++) {
            int o = ((w * 2 + i) << 10) + (lane << 4);
            int r = o >> 6, c = o & 63;
            int sc = c ^ (((r >> 1) & 3) << 4);
            gll16((const char*)Bt + ((size_t)(n0 + r) * K + kt * 32) * 2 + sc,
                  (char*)&Bs[buf][0] + ((w * 2 + i) << 10));
        }
    };

    f32x4 acc[4][4] = {};
    stage(0, 0);
    __syncthreads();
    int buf = 0;
    for (int kt = 0; kt < NK; kt++) {
        if (kt + 1 < NK) stage(buf ^ 1, kt + 1);
        const char* as = (const char*)&As[buf][0];
        const char* bs = (const char*)&Bs[buf][0];
        bf16x8 a[4], b[4];
#pragma unroll
        for (int mi = 0; mi < 4; mi++) {
            int r = wr * 64 + mi * 16 + rr;
            a[mi] = *(const bf16x8*)(as + r * 64 + ((qhi << 4) ^ (((r >> 1) & 3) << 4)));
        }
#pragma unroll
        for (int ni = 0; ni < 4; ni++) {
            int r = wc * 64 + ni * 16 + rr;
            b[ni] = *(const bf16x8*)(bs + r * 64 + ((qhi << 4) ^ (((r >> 1) & 3) << 4)));
        }
        if (vt) {
#pragma unroll
            for (int mi = 0; mi < 4; mi++)
#pragma unroll
                for (int ni = 0; ni < 4; ni++)
                    acc[mi][ni] = __builtin_amdgcn_mfma_f32_16x16x32_bf16(a[mi], b[ni], acc[mi][ni], 0, 0, 0);
        } else {
#pragma unroll
            for (int mi = 0; mi < 4; mi++)
#pragma unroll
                for (int ni = 0; ni < 4; ni++)
                    acc[mi][ni] = __builtin_amdgcn_mfma_f32_16x16x32_bf16(b[ni], a[mi], acc[mi][ni], 0, 0, 0);
        }
        __syncthreads();
        buf ^= 1;
    }

    if (MODE == 1) {
#pragma unroll
        for (int mi = 0; mi < 4; mi++) {
            int m = m0 + wr * 64 + mi * 16 + rr;
#pragma unroll
            for (int ni = 0; ni < 4; ni++) {
                int n = n0 + wc * 64 + ni * 16 + qhi * 4;
                f32x4 o = acc[mi][ni];
                __builtin_nontemporal_store(o, (f32x4*)((float*)O + (size_t)m * 1024 + n));
            }
        }
    } else if (vt) {
        unsigned short* Vt = (unsigned short*)O;
#pragma unroll
        for (int mi = 0; mi < 4; mi++) {
            int m = m0 + wr * 64 + mi * 16 + qhi * 4;
#pragma unroll
            for (int ni = 0; ni < 4; ni++) {
                int n = n0 + wc * 64 + ni * 16 + rr;
                int bh = (m >> 11) * 16 + (n >> 6);
                *(uint2*)(Vt + ((size_t)bh * 64 + (n & 63)) * 2048 + (m & 2047)) = pk4(acc[mi][ni]);
            }
        }
    } else {
        unsigned short* Oh = (unsigned short*)O;
#pragma unroll
        for (int mi = 0; mi < 4; mi++) {
            int m = m0 + wr * 64 + mi * 16 + rr;
#pragma unroll
            for (int ni = 0; ni < 4; ni++) {
                int n = n0 + wc * 64 + ni * 16 + qhi * 4;
                size_t idx = (((size_t)((m >> 11) * 16 + (n >> 6))) * 2048 + (m & 2047)) * 64 + (n & 63);
                *(uint2*)(Oh + idx) = pk4(acc[mi][ni]);
            }
        }
    }
}

// ------- attention: 2-chain pipeline, 128 q-rows/block (2 tiles of 64), 4 waves -------
// Phase A: pass1(tile0). Phase B: pass2(tile0) MERGED with pass1(tile1) — shared K
// frags/staging. Phase C: pass2(tile1). Scores are base-2 (log2e folded into wq).
// attn stores: per-wave LDS transpose -> 4x (4 rows x 256B) nontemporal stores.
__global__ __launch_bounds__(256, 3) void attn2(
    const unsigned short* __restrict__ Qh, const unsigned short* __restrict__ Kh,
    const unsigned short* __restrict__ Vt, float* __restrict__ attn,
    unsigned short* __restrict__ ctx)
{
    __shared__ unsigned short Ks[2][64 * 64];   // [kc][d], swizzled 128B rows
    __shared__ unsigned short Vs[2][64 * 64];   // [d][kc], swizzled
    __shared__ float St[4][1024];               // per-wave 16x64 fp32 staging, slot^rr swizzle
    const int t = threadIdx.x, lane = t & 63, w = t >> 6;
    int bid = blockIdx.x;
    int rm = (bid & 7) * 128 + (bid >> 3);      // XCD swizzle
    int bh = rm >> 4, rb = rm & 15;
    int qhi = lane >> 4, rr = lane & 15;
    int q00 = rb * 128 + w * 16;                // tile0 rows for this wave
    int q01 = q00 + 64;                         // tile1 rows

    const unsigned short* qb0 = Qh + ((size_t)bh * 2048 + q00 + rr) * 64;
    const unsigned short* qb1 = Qh + ((size_t)bh * 2048 + q01 + rr) * 64;
    bf16x8 aqA0 = *(const bf16x8*)(qb0 + qhi * 8);
    bf16x8 aqA1 = *(const bf16x8*)(qb0 + 32 + qhi * 8);
    bf16x8 aqB0 = *(const bf16x8*)(qb1 + qhi * 8);
    bf16x8 aqB1 = *(const bf16x8*)(qb1 + 32 + qhi * 8);

    auto stageK = [&](int buf, int ct) {
#pragma unroll
        for (int i = 0; i < 2; i++) {
            int o = ((w * 2 + i) << 10) + (lane << 4);
            int r = o >> 7, c = o & 127;
            int sc = c ^ ((r & 7) << 4);
            gll16((const char*)Kh + (size_t)(bh * 2048 + ct * 64 + r) * 128 + sc,
                  (char*)&Ks[buf][0] + ((w * 2 + i) << 10));
        }
    };
    auto stageV = [&](int buf, int ct) {
#pragma unroll
        for (int i = 0; i < 2; i++) {
            int o = ((w * 2 + i) << 10) + (lane << 4);
            int r = o >> 7, c = o & 127;
            int sc = c ^ ((r & 7) << 4);
            gll16((const char*)Vt + (size_t)(bh * 64 + r) * 4096 + ct * 128 + sc,
                  (char*)&Vs[buf][0] + ((w * 2 + i) << 10));
        }
    };

    float* ab = attn + (size_t)bh * 2048 * 2048;
    float* stw = &St[w][0];

    // ---- phase A: pass1(tile0) ----
    f32x4 sv = {0.f, 0.f, 0.f, 0.f};
    stageK(0, 0);
    __syncthreads();
    int buf = 0;
    for (int ct = 0; ct < 32; ct++) {
        if (ct < 31) stageK(buf ^ 1, ct + 1);
        const char* ks = (const char*)&Ks[buf][0];
#pragma unroll
        for (int n = 0; n < 4; n++) {
            int r = n * 16 + rr;
            int sw = (r & 7) << 4;
            bf16x8 b0 = *(const bf16x8*)(ks + r * 128 + ((qhi << 4) ^ sw));
            bf16x8 b1 = *(const bf16x8*)(ks + r * 128 + ((64 | (qhi << 4)) ^ sw));
            f32x4 z4 = {0.f, 0.f, 0.f, 0.f};
            f32x4 s = __builtin_amdgcn_mfma_f32_16x16x32_bf16(b0, aqA0, z4, 0, 0, 0);
            s = __builtin_amdgcn_mfma_f32_16x16x32_bf16(b1, aqA1, s, 0, 0, 0);
#pragma unroll
            for (int j = 0; j < 4; j++) sv[j] += exp2f(s[j]);
        }
        __syncthreads();
        buf ^= 1;
    }
    float lsum = sv[0] + sv[1] + sv[2] + sv[3];
    lsum += __shfl_xor(lsum, 16);
    lsum += __shfl_xor(lsum, 32);
    float lr2a = -__log2f(lsum);

    // ---- phase B: pass2(tile0) merged with pass1(tile1); shared K frags ----
    f32x4 sv1 = {0.f, 0.f, 0.f, 0.f};
    f32x4 acco[4] = {};
    stageK(0, 0); stageV(0, 0);
    __syncthreads();
    buf = 0;
    for (int ct = 0; ct < 32; ct++) {
        if (ct < 31) { stageK(buf ^ 1, ct + 1); stageV(buf ^ 1, ct + 1); }
        const char* ks = (const char*)&Ks[buf][0];
        f32x4 s0[4];
#pragma unroll
        for (int n = 0; n < 4; n++) {
            int r = n * 16 + rr;
            int sw = (r & 7) << 4;
            bf16x8 b0 = *(const bf16x8*)(ks + r * 128 + ((qhi << 4) ^ sw));
            bf16x8 b1 = *(const bf16x8*)(ks + r * 128 + ((64 | (qhi << 4)) ^ sw));
            f32x4 z4 = {0.f, 0.f, 0.f, 0.f};
            s0[n] = __builtin_amdgcn_mfma_f32_16x16x32_bf16(b0, aqA0, z4, 0, 0, 0);
            s0[n] = __builtin_amdgcn_mfma_f32_16x16x32_bf16(b1, aqA1, s0[n], 0, 0, 0);
            f32x4 s1 = __builtin_amdgcn_mfma_f32_16x16x32_bf16(b0, aqB0, z4, 0, 0, 0);
            s1 = __builtin_amdgcn_mfma_f32_16x16x32_bf16(b1, aqB1, s1, 0, 0, 0);
#pragma unroll
            for (int j = 0; j < 4; j++) sv1[j] += exp2f(s1[j]);
        }
        unsigned wA[4], wB[4];
#pragma unroll
        for (int n = 0; n < 4; n++) {
            f32x4 pv;
#pragma unroll
            for (int j = 0; j < 4; j++) pv[j] = exp2f(s0[n][j] + lr2a);
            *(f32x4*)(stw + rr * 64 + (((n * 4 + qhi) ^ rr) << 2)) = pv;
            asm("v_cvt_pk_bf16_f32 %0, %1, %2" : "=v"(wA[n]) : "v"(pv[0]), "v"(pv[1]));
            asm("v_cvt_pk_bf16_f32 %0, %1, %2" : "=v"(wB[n]) : "v"(pv[2]), "v"(pv[3]));
        }
        const char* vs = (const char*)&Vs[buf][0];
#pragma unroll
        for (int kb = 0; kb < 2; kb++) {
            u32x4 fw = {wA[2 * kb], wB[2 * kb], wA[2 * kb + 1], wB[2 * kb + 1]};
            bf16x8 pf = *(bf16x8*)&fw;
#pragma unroll
            for (int db = 0; db < 4; db++) {
                int r = db * 16 + rr;
                int sw = (r & 7) << 4;
                uint2 lo8 = *(const uint2*)(vs + r * 128 + ((kb * 64 + qhi * 8) ^ sw));
                uint2 hi8 = *(const uint2*)(vs + r * 128 + ((kb * 64 + 32 + qhi * 8) ^ sw));
                u32x4 vw = {lo8.x, lo8.y, hi8.x, hi8.y};
                bf16x8 vf = *(bf16x8*)&vw;
                acco[db] = __builtin_amdgcn_mfma_f32_16x16x32_bf16(vf, pf, acco[db], 0, 0, 0);
            }
        }
#pragma unroll
        for (int i = 0; i < 4; i++) {
            int r = 4 * i + qhi;
            f32x4 vvv = *(const f32x4*)(stw + r * 64 + ((rr ^ r) << 2));
            __builtin_nontemporal_store(vvv,
                (f32x4*)(ab + (size_t)(q00 + r) * 2048 + ct * 64 + rr * 4));
        }
        asm volatile("s_waitcnt vmcnt(4)" ::: "memory");
        __builtin_amdgcn_s_barrier();
        buf ^= 1;
    }
    int b_ = bh >> 4, h_ = bh & 15;
    {
        unsigned short* cw = ctx + ((size_t)b_ * 2048 + q00 + rr) * 1024 + h_ * 64;
#pragma unroll
        for (int db = 0; db < 4; db++)
            *(uint2*)(cw + db * 16 + qhi * 4) = pk4(acco[db]);
    }
    float lsum1 = sv1[0] + sv1[1] + sv1[2] + sv1[3];
    lsum1 += __shfl_xor(lsum1, 16);
    lsum1 += __shfl_xor(lsum1, 32);
    float lr2b = -__log2f(lsum1);

    // ---- phase C: pass2(tile1) ----
#pragma unroll
    for (int db = 0; db < 4; db++) acco[db] = (f32x4){0.f, 0.f, 0.f, 0.f};
    stageK(0, 0); stageV(0, 0);
    __syncthreads();
    buf = 0;
    for (int ct = 0; ct < 32; ct++) {
        if (ct < 31) { stageK(buf ^ 1, ct + 1); stageV(buf ^ 1, ct + 1); }
        const char* ks = (const char*)&Ks[buf][0];
        f32x4 s[4];
#pragma unroll
        for (int n = 0; n < 4; n++) {
            int r = n * 16 + rr;
            int sw = (r & 7) << 4;
            bf16x8 b0 = *(const bf16x8*)(ks + r * 128 + ((qhi << 4) ^ sw));
            bf16x8 b1 = *(const bf16x8*)(ks + r * 128 + ((64 | (qhi << 4)) ^ sw));
            f32x4 z4 = {0.f, 0.f, 0.f, 0.f};
            s[n] = __builtin_amdgcn_mfma_f32_16x16x32_bf16(b0, aqB0, z4, 0, 0, 0);
            s[n] = __builtin_amdgcn_mfma_f32_16x16x32_bf16(b1, aqB1, s[n], 0, 0, 0);
        }
        unsigned wA[4], wB[4];
#pragma unroll
        for (int n = 0; n < 4; n++) {
            f32x4 pv;
#pragma unroll
            for (int j = 0; j < 4; j++) pv[j] = exp2f(s[n][j] + lr2b);
            *(f32x4*)(stw + rr * 64 + (((n * 4 + qhi) ^ rr) << 2)) = pv;
            asm("v_cvt_pk_bf16_f32 %0, %1, %2" : "=v"(wA[n]) : "v"(pv[0]), "v"(pv[1]));
            asm("v_cvt_pk_bf16_f32 %0, %1, %2" : "=v"(wB[n]) : "v"(pv[2]), "v"(pv[3]));
        }
        const char* vs = (const char*)&Vs[buf][0];
#pragma unroll
        for (int kb = 0; kb < 2; kb++) {
            u32x4 fw = {wA[2 * kb], wB[2 * kb], wA[2 * kb + 1], wB[2 * kb + 1]};
            bf16x8 pf = *(bf16x8*)&fw;
#pragma unroll
            for (int db = 0; db < 4; db++) {
                int r = db * 16 + rr;
                int sw = (r & 7) << 4;
                uint2 lo8 = *(const uint2*)(vs + r * 128 + ((kb * 64 + qhi * 8) ^ sw));
                uint2 hi8 = *(const uint2*)(vs + r * 128 + ((kb * 64 + 32 + qhi * 8) ^ sw));
                u32x4 vw = {lo8.x, lo8.y, hi8.x, hi8.y};
                bf16x8 vf = *(bf16x8*)&vw;
                acco[db] = __builtin_amdgcn_mfma_f32_16x16x32_bf16(vf, pf, acco[db], 0, 0, 0);
            }
        }
#pragma unroll
        for (int i = 0; i < 4; i++) {
            int r = 4 * i + qhi;
            f32x4 vvv = *(const f32x4*)(stw + r * 64 + ((rr ^ r) << 2));
            __builtin_nontemporal_store(vvv,
                (f32x4*)(ab + (size_t)(q01 + r) * 2048 + ct * 64 + rr * 4));
        }
        asm volatile("s_waitcnt vmcnt(4)" ::: "memory");
        __builtin_amdgcn_s_barrier();
        buf ^= 1;
    }
    {
        unsigned short* cw = ctx + ((size_t)b_ * 2048 + q01 + rr) * 1024 + h_ * 64;
#pragma unroll
        for (int db = 0; db < 4; db++)
            *(uint2*)(cw + db * 16 + qhi * 4) = pk4(acco[db]);
    }
}

extern "C" void kernel_launch(void* const* d_in, const int* in_sizes, int n_in,
                              void* d_out, int out_size, void* d_ws, size_t ws_size,
                              hipStream_t stream)
{
    (void)in_sizes; (void)n_in; (void)out_size; (void)ws_size;
    const float* q  = (const float*)d_in[0];
    const float* k  = (const float*)d_in[1];
    const float* v  = (const float*)d_in[2];
    const float* wq = (const float*)d_in[3];
    const float* wk = (const float*)d_in[4];
    const float* wv = (const float*)d_in[5];
    const float* wo = (const float*)d_in[6];
    char* ws = (char*)d_ws;
    const size_t M1 = 1ull << 20;
    unsigned short* qbf = (unsigned short*)(ws);
    unsigned short* kbf = (unsigned short*)(ws + 16 * M1);
    unsigned short* vbf = (unsigned short*)(ws + 32 * M1);
    unsigned short* wqt = (unsigned short*)(ws + 48 * M1);
    unsigned short* wkt = (unsigned short*)(ws + 50 * M1);
    unsigned short* wvt = (unsigned short*)(ws + 52 * M1);
    unsigned short* wot = (unsigned short*)(ws + 54 * M1);
    unsigned short* Qh  = (unsigned short*)(ws + 56 * M1);
    unsigned short* Kh  = (unsigned short*)(ws + 72 * M1);
    unsigned short* Vt  = (unsigned short*)(ws + 88 * M1);
    unsigned short* ctx = kbf;    // dead after projections
    float* out0 = (float*)d_out;
    float* attn = out0 + (size_t)8192 * 1024;

    cvt3<<<12288, 256, 0, stream>>>(q, k, v, qbf, kbf, vbf);
    wtrans<<<1024, 256, 0, stream>>>(wq, wk, wv, wo, wqt, wkt, wvt, wot);
    gemm128<0><<<dim3(512, 1, 3), 256, 0, stream>>>(qbf, kbf, vbf, wqt, wkt, wvt,
                                                    (void*)Qh, (void*)Kh, (void*)Vt);
    attn2<<<1024, 256, 0, stream>>>(Qh, Kh, Vt, attn, ctx);
    gemm128<1><<<dim3(512, 1, 1), 256, 0, stream>>>(ctx, ctx, ctx, wot, wot, wot,
                                                    (void*)out0, (void*)out0, (void*)out0);
}